// Round 1
// baseline (462.096 us; speedup 1.0000x reference)
//
#include <hip/hip_runtime.h>
#include <stdint.h>

#define LDK 136   // padded LDS K-stride (128 + 8 bf16) -> even 8-lane/bank-group for b128 frag reads

typedef __attribute__((ext_vector_type(4))) float f32x4;
typedef __attribute__((ext_vector_type(8))) short bf16x8;

__device__ inline unsigned short f2bf_rtne(float f) {
    union { float f; unsigned u; } v; v.f = f;
    unsigned u = v.u;
    u += 0x7fffu + ((u >> 16) & 1u);
    return (unsigned short)(u >> 16);
}
__device__ inline float bf2f(unsigned short h) {
    union { float f; unsigned u; } v; v.u = ((unsigned)h) << 16;
    return v.f;
}

// ---------------------------------------------------------------------------
// prep: weight transpose+bf16 cast, mask decode, num_atoms
// grid: 64 blocks x 256 (block 0 also handles the mask)
// ---------------------------------------------------------------------------
__global__ void prep_kernel(const float* __restrict__ relW1, const float* __restrict__ relW2,
                            const float* __restrict__ pwW1, const float* __restrict__ pwW2,
                            const void* __restrict__ maskp,
                            float* __restrict__ maskf, float* __restrict__ na,
                            unsigned short* __restrict__ w1T_rel, unsigned short* __restrict__ w2T_rel,
                            unsigned short* __restrict__ w1T_pw, unsigned short* __restrict__ w2T_pw) {
    int t = threadIdx.x;
    const float* srcs[4] = {relW1, relW2, pwW1, pwW2};
    unsigned short* dsts[4] = {w1T_rel, w2T_rel, w1T_pw, w2T_pw};
    int e0 = blockIdx.x * 1024 + t;
#pragma unroll
    for (int i = 0; i < 4; ++i) {
        int e = e0 + i * 256;
        int mat = e >> 14, o = e & 16383;
        int n = o >> 7, k = o & 127;
        dsts[mat][o] = f2bf_rtne(srcs[mat][k * 128 + n]);   // wT[n][k] = W[k][n]
    }
    if (blockIdx.x == 0) {
        __shared__ int anyb;
        __shared__ float cnt[2];
        if (t == 0) anyb = 0;
        if (t < 2) cnt[t] = 0.f;
        __syncthreads();
        // robust mask dtype detection: bool8 has nonzero bytes in the first 1024
        // bytes (indices 448..511 are true); int32/float32 storage has the first
        // 256 elements == 0 there.
        const unsigned char* mb = (const unsigned char*)maskp;
        int la = 0;
        for (int i = t; i < 1024; i += 256) la |= mb[i];
        if (la) atomicOr(&anyb, 1);
        __syncthreads();
        bool isbyte = (anyb != 0);
        const int* mi = (const int*)maskp;
        float loc0 = 0.f, loc1 = 0.f;
        for (int i = t; i < 1024; i += 256) {
            int v = isbyte ? (int)mb[i] : mi[i];
            float um = (v != 0) ? 0.f : 1.f;   // unmasked = !masked
            maskf[i] = um;
            if (i < 512) loc0 += um; else loc1 += um;
        }
        atomicAdd(&cnt[0], loc0);
        atomicAdd(&cnt[1], loc1);
        __syncthreads();
        if (t < 2) na[t] = cnt[t];
    }
}

// ---------------------------------------------------------------------------
// fused 3-layer MLP: rows x (128 ->relu-> 128 ->relu-> 4)
// block = 256 thr (4 waves), 4 tiles of 64 rows, weights in VGPR fragments.
// Computes H^T = W^T * X^T per layer: D row = hidden unit, D col = data row,
// so each lane's 4 acc regs are 4 consecutive hidden units -> short4 LDS write.
// ---------------------------------------------------------------------------
__global__ __launch_bounds__(256, 2)
void mlp_kernel(const float* __restrict__ X,
                const unsigned short* __restrict__ w1T,
                const unsigned short* __restrict__ w2T,
                const float* __restrict__ W3, const float* __restrict__ b1,
                const float* __restrict__ b2, const float* __restrict__ b3,
                float* __restrict__ Sout) {
    __shared__ short xs[2][64 * LDK];
    __shared__ short hs[64 * LDK];
    __shared__ float w3s[4 * 128];
    __shared__ float bs1[128], bs2[128], b3s[4];

    int t = threadIdx.x;
    int w = t >> 6, lane = t & 63, q = lane >> 4, col = lane & 15;

    if (t < 128) { bs1[t] = b1[t]; bs2[t] = b2[t]; }
    if (t < 4) b3s[t] = b3[t];
    for (int i = t; i < 512; i += 256) { int c = i >> 2, k = i & 3; w3s[k * 128 + c] = W3[i]; }

    // A-operand (weight) fragments live in registers for the whole block.
    // A[i=n][k]: n = base + (lane&15), k = kc*32 + (lane>>4)*8 + j  (16B contiguous)
    bf16x8 w1f[2][4], w2f[2][4];
#pragma unroll
    for (int tn = 0; tn < 2; ++tn)
#pragma unroll
        for (int kc = 0; kc < 4; ++kc) {
            int n = w * 32 + tn * 16 + col;
            int kk = kc * 32 + q * 8;
            w1f[tn][kc] = *(const bf16x8*)&w1T[n * 128 + kk];
            w2f[tn][kc] = *(const bf16x8*)&w2T[n * 128 + kk];
        }

    long rowbase = (long)blockIdx.x * 256;
    int r0 = t >> 5, cg = t & 31;

    float4 px[8];
    {
        const float4* Xg = (const float4*)(X + rowbase * 128);
#pragma unroll
        for (int i = 0; i < 8; ++i) px[i] = Xg[(r0 + 8 * i) * 32 + cg];
#pragma unroll
        for (int i = 0; i < 8; ++i) {
            float4 v = px[i];
            short4 s4 = make_short4((short)f2bf_rtne(v.x), (short)f2bf_rtne(v.y),
                                    (short)f2bf_rtne(v.z), (short)f2bf_rtne(v.w));
            *(short4*)&xs[0][(r0 + 8 * i) * LDK + cg * 4] = s4;
        }
    }
    __syncthreads();

    for (int tile = 0; tile < 4; ++tile) {
        int buf = tile & 1;
        if (tile < 3) {  // prefetch next X tile into regs
            const float4* Xg2 = (const float4*)(X + (rowbase + (long)(tile + 1) * 64) * 128);
#pragma unroll
            for (int i = 0; i < 8; ++i) px[i] = Xg2[(r0 + 8 * i) * 32 + cg];
        }

        // ---- layer 1 ----
        f32x4 acc[2][4];
#pragma unroll
        for (int tn = 0; tn < 2; ++tn)
#pragma unroll
            for (int tm = 0; tm < 4; ++tm) acc[tn][tm] = (f32x4)(0.f);
#pragma unroll
        for (int kc = 0; kc < 4; ++kc) {
            bf16x8 bf[4];
#pragma unroll
            for (int tm = 0; tm < 4; ++tm)
                bf[tm] = *(const bf16x8*)&xs[buf][(tm * 16 + col) * LDK + kc * 32 + q * 8];
#pragma unroll
            for (int tn = 0; tn < 2; ++tn)
#pragma unroll
                for (int tm = 0; tm < 4; ++tm)
                    acc[tn][tm] = __builtin_amdgcn_mfma_f32_16x16x32_bf16(w1f[tn][kc], bf[tm], acc[tn][tm], 0, 0, 0);
        }
        __syncthreads();  // A: all waves past layer1 reads (and past prev tile's layer3 hs reads)

        // epilogue 1: bias + relu -> bf16 -> hs[m][n], packed 4 consecutive n
#pragma unroll
        for (int tn = 0; tn < 2; ++tn)
#pragma unroll
            for (int tm = 0; tm < 4; ++tm) {
                int n0 = w * 32 + tn * 16 + q * 4;
                int m = tm * 16 + col;
                float4 bb = *(const float4*)&bs1[n0];
                short4 s4 = make_short4(
                    (short)f2bf_rtne(fmaxf(acc[tn][tm][0] + bb.x, 0.f)),
                    (short)f2bf_rtne(fmaxf(acc[tn][tm][1] + bb.y, 0.f)),
                    (short)f2bf_rtne(fmaxf(acc[tn][tm][2] + bb.z, 0.f)),
                    (short)f2bf_rtne(fmaxf(acc[tn][tm][3] + bb.w, 0.f)));
                *(short4*)&hs[m * LDK + n0] = s4;
            }
        if (tile < 3) {  // stage prefetched X into the other buffer
#pragma unroll
            for (int i = 0; i < 8; ++i) {
                float4 v = px[i];
                short4 s4 = make_short4((short)f2bf_rtne(v.x), (short)f2bf_rtne(v.y),
                                        (short)f2bf_rtne(v.z), (short)f2bf_rtne(v.w));
                *(short4*)&xs[1 - buf][(r0 + 8 * i) * LDK + cg * 4] = s4;
            }
        }
        __syncthreads();  // B: hs (H1) visible

        // ---- layer 2 ----
        f32x4 acc2[2][4];
#pragma unroll
        for (int tn = 0; tn < 2; ++tn)
#pragma unroll
            for (int tm = 0; tm < 4; ++tm) acc2[tn][tm] = (f32x4)(0.f);
#pragma unroll
        for (int kc = 0; kc < 4; ++kc) {
            bf16x8 bf[4];
#pragma unroll
            for (int tm = 0; tm < 4; ++tm)
                bf[tm] = *(const bf16x8*)&hs[(tm * 16 + col) * LDK + kc * 32 + q * 8];
#pragma unroll
            for (int tn = 0; tn < 2; ++tn)
#pragma unroll
                for (int tm = 0; tm < 4; ++tm)
                    acc2[tn][tm] = __builtin_amdgcn_mfma_f32_16x16x32_bf16(w2f[tn][kc], bf[tm], acc2[tn][tm], 0, 0, 0);
        }
        __syncthreads();  // C: layer2 reads done, hs writable

        // epilogue 2 -> hs (H2)
#pragma unroll
        for (int tn = 0; tn < 2; ++tn)
#pragma unroll
            for (int tm = 0; tm < 4; ++tm) {
                int n0 = w * 32 + tn * 16 + q * 4;
                int m = tm * 16 + col;
                float4 bb = *(const float4*)&bs2[n0];
                short4 s4 = make_short4(
                    (short)f2bf_rtne(fmaxf(acc2[tn][tm][0] + bb.x, 0.f)),
                    (short)f2bf_rtne(fmaxf(acc2[tn][tm][1] + bb.y, 0.f)),
                    (short)f2bf_rtne(fmaxf(acc2[tn][tm][2] + bb.z, 0.f)),
                    (short)f2bf_rtne(fmaxf(acc2[tn][tm][3] + bb.w, 0.f)));
                *(short4*)&hs[m * LDK + n0] = s4;
            }
        __syncthreads();  // D: H2 visible

        // ---- layer 3 (128 -> 4), f32 vector ----
        {
            int row = t >> 2, k = t & 3;
            float s = b3s[k];
#pragma unroll
            for (int cc = 0; cc < 16; ++cc) {
                bf16x8 h8 = *(const bf16x8*)&hs[row * LDK + cc * 8];
                float4 wa = *(const float4*)&w3s[k * 128 + cc * 8];
                float4 wb = *(const float4*)&w3s[k * 128 + cc * 8 + 4];
                s += bf2f((unsigned short)h8[0]) * wa.x + bf2f((unsigned short)h8[1]) * wa.y +
                     bf2f((unsigned short)h8[2]) * wa.z + bf2f((unsigned short)h8[3]) * wa.w +
                     bf2f((unsigned short)h8[4]) * wb.x + bf2f((unsigned short)h8[5]) * wb.y +
                     bf2f((unsigned short)h8[6]) * wb.z + bf2f((unsigned short)h8[7]) * wb.w;
            }
            Sout[(rowbase + (long)tile * 64) * 4 + t] = s;  // row*4+k == t
        }
        // next iteration's barrier A guards hs against early overwrite
    }
}

// ---------------------------------------------------------------------------
// reduce: out[b,i,c] = (sum_k pwb*S_pw)/na + (sum_k sum_j S_rel*relb*mask)/na^2
// grid: B*N = 1024 blocks x 256
// ---------------------------------------------------------------------------
__global__ __launch_bounds__(256)
void reduce_kernel(const float* __restrict__ S_rel, const float* __restrict__ S_pw,
                   const float* __restrict__ rel_basis, const float* __restrict__ pw_basis,
                   const float* __restrict__ maskf, const float* __restrict__ na,
                   float* __restrict__ out) {
    int bi = blockIdx.x;      // b*512 + i
    int b = bi >> 9;
    int t = threadIdx.x;
    float part[12];
#pragma unroll
    for (int r = 0; r < 12; ++r) part[r] = 0.f;

    for (int j = t; j < 512; j += 256) {
        float m = maskf[b * 512 + j];
        long r = (long)bi * 512 + j;
        float4 s4 = *(const float4*)&S_rel[r * 4];
        const float* bp = &rel_basis[r * 12];
        float4 q0 = *(const float4*)&bp[0];
        float4 q1 = *(const float4*)&bp[4];
        float4 q2 = *(const float4*)&bp[8];
        float s0 = s4.x * m, s1 = s4.y * m, s2 = s4.z * m, s3 = s4.w * m;
        part[0] += s0 * q0.x; part[1] += s0 * q0.y; part[2]  += s0 * q0.z;
        part[3] += s1 * q0.w; part[4] += s1 * q1.x; part[5]  += s1 * q1.y;
        part[6] += s2 * q1.z; part[7] += s2 * q1.w; part[8]  += s2 * q2.x;
        part[9] += s3 * q2.y; part[10] += s3 * q2.z; part[11] += s3 * q2.w;
    }

    __shared__ float red[256][12];
#pragma unroll
    for (int r = 0; r < 12; ++r) red[t][r] = part[r];
    __syncthreads();
    for (int s = 128; s > 0; s >>= 1) {
        if (t < s) {
#pragma unroll
            for (int r = 0; r < 12; ++r) red[t][r] += red[t + s][r];
        }
        __syncthreads();
    }
    if (t < 3) {
        float NA = na[b];
        float accp = 0.f, rel = 0.f;
#pragma unroll
        for (int k = 0; k < 4; ++k) {
            accp += pw_basis[bi * 12 + k * 3 + t] * S_pw[bi * 4 + k];
            rel  += red[0][k * 3 + t];
        }
        out[bi * 3 + t] = accp / NA + rel / (NA * NA);
    }
}

// ---------------------------------------------------------------------------
extern "C" void kernel_launch(void* const* d_in, const int* in_sizes, int n_in,
                              void* d_out, int out_size, void* d_ws, size_t ws_size,
                              hipStream_t stream) {
    const float* pw_feat   = (const float*)d_in[0];
    const float* rel_feat  = (const float*)d_in[1];
    const float* pw_basis  = (const float*)d_in[2];
    const float* rel_basis = (const float*)d_in[3];
    const float* pw_W1 = (const float*)d_in[4];
    const float* pw_b1 = (const float*)d_in[5];
    const float* pw_W2 = (const float*)d_in[6];
    const float* pw_b2 = (const float*)d_in[7];
    const float* pw_W3 = (const float*)d_in[8];
    const float* pw_b3 = (const float*)d_in[9];
    const float* rel_W1 = (const float*)d_in[10];
    const float* rel_b1 = (const float*)d_in[11];
    const float* rel_W2 = (const float*)d_in[12];
    const float* rel_b2 = (const float*)d_in[13];
    const float* rel_W3 = (const float*)d_in[14];
    const float* rel_b3 = (const float*)d_in[15];
    const void*  maskp  = d_in[16];
    float* out = (float*)d_out;

    char* ws = (char*)d_ws;
    float* maskf = (float*)(ws + 0);                      // 1024 f32
    float* na    = (float*)(ws + 4096);                   // 2 f32
    unsigned short* w1T_rel = (unsigned short*)(ws + 4352);
    unsigned short* w2T_rel = (unsigned short*)(ws + 4352 + 32768);
    unsigned short* w1T_pw  = (unsigned short*)(ws + 4352 + 65536);
    unsigned short* w2T_pw  = (unsigned short*)(ws + 4352 + 98304);
    float* S_pw  = (float*)(ws + 4352 + 131072);          // 1024*4 f32
    float* S_rel = (float*)(ws + 4352 + 131072 + 16384);  // 524288*4 f32 (8 MB)

    prep_kernel<<<64, 256, 0, stream>>>(rel_W1, rel_W2, pw_W1, pw_W2, maskp,
                                        maskf, na, w1T_rel, w2T_rel, w1T_pw, w2T_pw);
    mlp_kernel<<<2048, 256, 0, stream>>>(rel_feat, w1T_rel, w2T_rel, rel_W3,
                                         rel_b1, rel_b2, rel_b3, S_rel);
    mlp_kernel<<<4, 256, 0, stream>>>(pw_feat, w1T_pw, w2T_pw, pw_W3,
                                      pw_b1, pw_b2, pw_b3, S_pw);
    reduce_kernel<<<1024, 256, 0, stream>>>(S_rel, S_pw, rel_basis, pw_basis,
                                            maskf, na, out);
}

// Round 2
// 445.999 us; speedup vs baseline: 1.0361x; 1.0361x over previous
//
#include <hip/hip_runtime.h>
#include <stdint.h>

#define LDK 136   // padded LDS K-stride (shorts): byte stride 272 -> b128 frag reads spread 8 lanes/4-bank group

typedef __attribute__((ext_vector_type(4))) float f32x4;
typedef __attribute__((ext_vector_type(8))) short bf16x8;

__device__ inline unsigned short f2bf_rtne(float f) {
    union { float f; unsigned u; } v; v.f = f;
    unsigned u = v.u;
    u += 0x7fffu + ((u >> 16) & 1u);
    return (unsigned short)(u >> 16);
}

// ---------------------------------------------------------------------------
// prep: weight transpose+bf16 cast (W1,W2 -> [n][k]; W3 -> padded 16x128 A-layout),
// mask decode, num_atoms. grid: 64 blocks x 256.
// ---------------------------------------------------------------------------
__global__ void prep_kernel(const float* __restrict__ relW1, const float* __restrict__ relW2,
                            const float* __restrict__ pwW1, const float* __restrict__ pwW2,
                            const float* __restrict__ relW3, const float* __restrict__ pwW3,
                            const void* __restrict__ maskp,
                            float* __restrict__ maskf, float* __restrict__ na,
                            unsigned short* __restrict__ w1T_rel, unsigned short* __restrict__ w2T_rel,
                            unsigned short* __restrict__ w1T_pw, unsigned short* __restrict__ w2T_pw,
                            unsigned short* __restrict__ w3T_rel, unsigned short* __restrict__ w3T_pw) {
    int t = threadIdx.x;
    const float* srcs[4] = {relW1, relW2, pwW1, pwW2};
    unsigned short* dsts[4] = {w1T_rel, w2T_rel, w1T_pw, w2T_pw};
    int e0 = blockIdx.x * 1024 + t;
#pragma unroll
    for (int i = 0; i < 4; ++i) {
        int e = e0 + i * 256;
        int mat = e >> 14, o = e & 16383;
        int n = o >> 7, k = o & 127;
        dsts[mat][o] = f2bf_rtne(srcs[mat][k * 128 + n]);   // wT[n][k] = W[k][n]
    }
    if (blockIdx.x == 1) {
        // W3^T padded to 16 rows x 128 cols (rows 4..15 zero), bf16
        for (int i = t; i < 2048; i += 256) {
            int r = i >> 7, h = i & 127;
            w3T_rel[i] = (r < 4) ? f2bf_rtne(relW3[h * 4 + r]) : (unsigned short)0;
            w3T_pw[i]  = (r < 4) ? f2bf_rtne(pwW3[h * 4 + r])  : (unsigned short)0;
        }
    }
    if (blockIdx.x == 0) {
        __shared__ int anyb;
        __shared__ float cnt[2];
        if (t == 0) anyb = 0;
        if (t < 2) cnt[t] = 0.f;
        __syncthreads();
        // robust mask dtype detection: bool8 storage has nonzero bytes within the
        // first 1024 bytes (indices 448..511 true); int32 storage is all-zero there.
        const unsigned char* mb = (const unsigned char*)maskp;
        int la = 0;
        for (int i = t; i < 1024; i += 256) la |= mb[i];
        if (la) atomicOr(&anyb, 1);
        __syncthreads();
        bool isbyte = (anyb != 0);
        const int* mi = (const int*)maskp;
        float loc0 = 0.f, loc1 = 0.f;
        for (int i = t; i < 1024; i += 256) {
            int v = isbyte ? (int)mb[i] : mi[i];
            float um = (v != 0) ? 0.f : 1.f;   // unmasked = !masked
            maskf[i] = um;
            if (i < 512) loc0 += um; else loc1 += um;
        }
        atomicAdd(&cnt[0], loc0);
        atomicAdd(&cnt[1], loc1);
        __syncthreads();
        if (t < 2) na[t] = cnt[t];
    }
}

// ---------------------------------------------------------------------------
// fused 3-layer MLP: rows x (128 ->relu-> 128 ->relu-> 4), all layers MFMA.
// block = 256 thr (4 waves), 4 tiles of 64 rows.
// W1/W2/W3 fragments live in VGPRs for the whole block. Single xs buffer
// (register px prefetch), ping-pong hs -> 3 barriers/tile.
// ---------------------------------------------------------------------------
__global__ __launch_bounds__(256, 2)
void mlp_kernel(const float* __restrict__ X,
                const unsigned short* __restrict__ w1T,
                const unsigned short* __restrict__ w2T,
                const unsigned short* __restrict__ w3T,
                const float* __restrict__ b1, const float* __restrict__ b2,
                const float* __restrict__ b3,
                float* __restrict__ Sout) {
    __shared__ short xs[64 * LDK];
    __shared__ short hs[2][64 * LDK];
    __shared__ float bs1[128], bs2[128], b3s[4];

    int t = threadIdx.x;
    int w = t >> 6, lane = t & 63, q = lane >> 4, col = lane & 15;

    if (t < 128) { bs1[t] = b1[t]; bs2[t] = b2[t]; }
    if (t < 4) b3s[t] = b3[t];

    // A-operand (weight) fragments: A[n][k], n = base+(lane&15), k = kc*32+(lane>>4)*8+j
    bf16x8 w1f[2][4], w2f[2][4], w3f[4];
#pragma unroll
    for (int tn = 0; tn < 2; ++tn)
#pragma unroll
        for (int kc = 0; kc < 4; ++kc) {
            int n = w * 32 + tn * 16 + col;
            int kk = kc * 32 + q * 8;
            w1f[tn][kc] = *(const bf16x8*)&w1T[n * 128 + kk];
            w2f[tn][kc] = *(const bf16x8*)&w2T[n * 128 + kk];
        }
#pragma unroll
    for (int kc = 0; kc < 4; ++kc)
        w3f[kc] = *(const bf16x8*)&w3T[col * 128 + kc * 32 + q * 8];

    long rowbase = (long)blockIdx.x * 256;
    int r0 = t >> 5, cg = t & 31;

    float4 px[8];
    {
        const float4* Xg = (const float4*)(X + rowbase * 128);
#pragma unroll
        for (int i = 0; i < 8; ++i) px[i] = Xg[(r0 + 8 * i) * 32 + cg];
#pragma unroll
        for (int i = 0; i < 8; ++i) {
            float4 v = px[i];
            short4 s4 = make_short4((short)f2bf_rtne(v.x), (short)f2bf_rtne(v.y),
                                    (short)f2bf_rtne(v.z), (short)f2bf_rtne(v.w));
            *(short4*)&xs[(r0 + 8 * i) * LDK + cg * 4] = s4;
        }
    }
    __syncthreads();

    for (int tile = 0; tile < 4; ++tile) {
        int hp = tile & 1;
        if (tile < 3) {  // prefetch next X tile into regs (cover = layer1 + epi1)
            const float4* Xg2 = (const float4*)(X + (rowbase + (long)(tile + 1) * 64) * 128);
#pragma unroll
            for (int i = 0; i < 8; ++i) px[i] = Xg2[(r0 + 8 * i) * 32 + cg];
        }

        // ---- layer 1: D = W1^T · X^T ----
        f32x4 acc[2][4];
#pragma unroll
        for (int tn = 0; tn < 2; ++tn)
#pragma unroll
            for (int tm = 0; tm < 4; ++tm) acc[tn][tm] = (f32x4)(0.f);
#pragma unroll
        for (int kc = 0; kc < 4; ++kc) {
            bf16x8 bf[4];
#pragma unroll
            for (int tm = 0; tm < 4; ++tm)
                bf[tm] = *(const bf16x8*)&xs[(tm * 16 + col) * LDK + kc * 32 + q * 8];
#pragma unroll
            for (int tn = 0; tn < 2; ++tn)
#pragma unroll
                for (int tm = 0; tm < 4; ++tm)
                    acc[tn][tm] = __builtin_amdgcn_mfma_f32_16x16x32_bf16(w1f[tn][kc], bf[tm], acc[tn][tm], 0, 0, 0);
        }

        // epilogue 1: bias+relu -> bf16 -> hs[hp] (prev reader was tile-2's L3; fenced)
#pragma unroll
        for (int tn = 0; tn < 2; ++tn)
#pragma unroll
            for (int tm = 0; tm < 4; ++tm) {
                int n0 = w * 32 + tn * 16 + q * 4;
                int m = tm * 16 + col;
                float4 bb = *(const float4*)&bs1[n0];
                short4 s4 = make_short4(
                    (short)f2bf_rtne(fmaxf(acc[tn][tm][0] + bb.x, 0.f)),
                    (short)f2bf_rtne(fmaxf(acc[tn][tm][1] + bb.y, 0.f)),
                    (short)f2bf_rtne(fmaxf(acc[tn][tm][2] + bb.z, 0.f)),
                    (short)f2bf_rtne(fmaxf(acc[tn][tm][3] + bb.w, 0.f)));
                *(short4*)&hs[hp][m * LDK + n0] = s4;
            }
        __syncthreads();  // AB: xs reads done (can restage) + hs[hp] H1 visible

        if (tile < 3) {  // stage prefetched X into (single) xs buffer
#pragma unroll
            for (int i = 0; i < 8; ++i) {
                float4 v = px[i];
                short4 s4 = make_short4((short)f2bf_rtne(v.x), (short)f2bf_rtne(v.y),
                                        (short)f2bf_rtne(v.z), (short)f2bf_rtne(v.w));
                *(short4*)&xs[(r0 + 8 * i) * LDK + cg * 4] = s4;
            }
        }

        // ---- layer 2: D = W2^T · H1^T ----
        f32x4 acc2[2][4];
#pragma unroll
        for (int tn = 0; tn < 2; ++tn)
#pragma unroll
            for (int tm = 0; tm < 4; ++tm) acc2[tn][tm] = (f32x4)(0.f);
#pragma unroll
        for (int kc = 0; kc < 4; ++kc) {
            bf16x8 bf[4];
#pragma unroll
            for (int tm = 0; tm < 4; ++tm)
                bf[tm] = *(const bf16x8*)&hs[hp][(tm * 16 + col) * LDK + kc * 32 + q * 8];
#pragma unroll
            for (int tn = 0; tn < 2; ++tn)
#pragma unroll
                for (int tm = 0; tm < 4; ++tm)
                    acc2[tn][tm] = __builtin_amdgcn_mfma_f32_16x16x32_bf16(w2f[tn][kc], bf[tm], acc2[tn][tm], 0, 0, 0);
        }
        __syncthreads();  // C: hs[hp] H1 reads done, may overwrite

        // epilogue 2 -> hs[hp] = H2
#pragma unroll
        for (int tn = 0; tn < 2; ++tn)
#pragma unroll
            for (int tm = 0; tm < 4; ++tm) {
                int n0 = w * 32 + tn * 16 + q * 4;
                int m = tm * 16 + col;
                float4 bb = *(const float4*)&bs2[n0];
                short4 s4 = make_short4(
                    (short)f2bf_rtne(fmaxf(acc2[tn][tm][0] + bb.x, 0.f)),
                    (short)f2bf_rtne(fmaxf(acc2[tn][tm][1] + bb.y, 0.f)),
                    (short)f2bf_rtne(fmaxf(acc2[tn][tm][2] + bb.z, 0.f)),
                    (short)f2bf_rtne(fmaxf(acc2[tn][tm][3] + bb.w, 0.f)));
                *(short4*)&hs[hp][m * LDK + n0] = s4;
            }
        __syncthreads();  // D: H2 visible

        // ---- layer 3: D = W3pad^T · H2^T  (4 MFMAs/wave, wave w owns rows w*16..) ----
        {
            f32x4 a3 = (f32x4)(0.f);
#pragma unroll
            for (int kc = 0; kc < 4; ++kc) {
                bf16x8 hb = *(const bf16x8*)&hs[hp][(w * 16 + col) * LDK + kc * 32 + q * 8];
                a3 = __builtin_amdgcn_mfma_f32_16x16x32_bf16(w3f[kc], hb, a3, 0, 0, 0);
            }
            if (q == 0) {  // rows 0..3 of D hold S[k][row]; lane col owns data row w*16+col
                long r = rowbase + (long)tile * 64 + w * 16 + col;
                *(float4*)&Sout[r * 4] = make_float4(a3[0] + b3s[0], a3[1] + b3s[1],
                                                     a3[2] + b3s[2], a3[3] + b3s[3]);
            }
        }
        // next tile's L1 reads xs staged above (fenced by C,D); epi1 writes hs[1-hp] (fenced)
    }
}

// ---------------------------------------------------------------------------
// reduce: out[b,i,c] = (sum_k pwb*S_pw)/na + (sum_k sum_j S_rel*relb*mask)/na^2
// grid: B*N = 1024 blocks x 256; wave shuffle reduction.
// ---------------------------------------------------------------------------
__global__ __launch_bounds__(256)
void reduce_kernel(const float* __restrict__ S_rel, const float* __restrict__ S_pw,
                   const float* __restrict__ rel_basis, const float* __restrict__ pw_basis,
                   const float* __restrict__ maskf, const float* __restrict__ na,
                   float* __restrict__ out) {
    int bi = blockIdx.x;      // b*512 + i
    int b = bi >> 9;
    int t = threadIdx.x;
    float part[12];
#pragma unroll
    for (int r = 0; r < 12; ++r) part[r] = 0.f;

    for (int j = t; j < 512; j += 256) {
        float m = maskf[b * 512 + j];
        long r = (long)bi * 512 + j;
        float4 s4 = *(const float4*)&S_rel[r * 4];
        const float* bp = &rel_basis[r * 12];
        float4 q0 = *(const float4*)&bp[0];
        float4 q1 = *(const float4*)&bp[4];
        float4 q2 = *(const float4*)&bp[8];
        float s0 = s4.x * m, s1 = s4.y * m, s2 = s4.z * m, s3 = s4.w * m;
        part[0] += s0 * q0.x; part[1] += s0 * q0.y; part[2]  += s0 * q0.z;
        part[3] += s1 * q0.w; part[4] += s1 * q1.x; part[5]  += s1 * q1.y;
        part[6] += s2 * q1.z; part[7] += s2 * q1.w; part[8]  += s2 * q2.x;
        part[9] += s3 * q2.y; part[10] += s3 * q2.z; part[11] += s3 * q2.w;
    }

#pragma unroll
    for (int s = 32; s > 0; s >>= 1)
#pragma unroll
        for (int r = 0; r < 12; ++r) part[r] += __shfl_down(part[r], s);

    __shared__ float red[4][12];
    int w = t >> 6, lane = t & 63;
    if (lane == 0)
#pragma unroll
        for (int r = 0; r < 12; ++r) red[w][r] = part[r];
    __syncthreads();

    if (t < 3) {
        float NA = na[b];
        float accp = 0.f, rel = 0.f;
#pragma unroll
        for (int k = 0; k < 4; ++k) {
            rel  += red[0][k * 3 + t] + red[1][k * 3 + t] + red[2][k * 3 + t] + red[3][k * 3 + t];
            accp += pw_basis[bi * 12 + k * 3 + t] * S_pw[bi * 4 + k];
        }
        out[bi * 3 + t] = accp / NA + rel / (NA * NA);
    }
}

// ---------------------------------------------------------------------------
extern "C" void kernel_launch(void* const* d_in, const int* in_sizes, int n_in,
                              void* d_out, int out_size, void* d_ws, size_t ws_size,
                              hipStream_t stream) {
    const float* pw_feat   = (const float*)d_in[0];
    const float* rel_feat  = (const float*)d_in[1];
    const float* pw_basis  = (const float*)d_in[2];
    const float* rel_basis = (const float*)d_in[3];
    const float* pw_W1 = (const float*)d_in[4];
    const float* pw_b1 = (const float*)d_in[5];
    const float* pw_W2 = (const float*)d_in[6];
    const float* pw_b2 = (const float*)d_in[7];
    const float* pw_W3 = (const float*)d_in[8];
    const float* pw_b3 = (const float*)d_in[9];
    const float* rel_W1 = (const float*)d_in[10];
    const float* rel_b1 = (const float*)d_in[11];
    const float* rel_W2 = (const float*)d_in[12];
    const float* rel_b2 = (const float*)d_in[13];
    const float* rel_W3 = (const float*)d_in[14];
    const float* rel_b3 = (const float*)d_in[15];
    const void*  maskp  = d_in[16];
    float* out = (float*)d_out;

    char* ws = (char*)d_ws;
    float* maskf = (float*)(ws + 0);                       // 1024 f32
    float* na    = (float*)(ws + 4096);                    // 2 f32
    unsigned short* w1T_rel = (unsigned short*)(ws + 4352);
    unsigned short* w2T_rel = (unsigned short*)(ws + 37120);
    unsigned short* w1T_pw  = (unsigned short*)(ws + 69888);
    unsigned short* w2T_pw  = (unsigned short*)(ws + 102656);
    unsigned short* w3T_rel = (unsigned short*)(ws + 135424);  // 16x128 bf16
    unsigned short* w3T_pw  = (unsigned short*)(ws + 139520);
    float* S_pw  = (float*)(ws + 143616);                  // 1024*4 f32
    float* S_rel = (float*)(ws + 160000);                  // 524288*4 f32 (8 MB)

    prep_kernel<<<64, 256, 0, stream>>>(rel_W1, rel_W2, pw_W1, pw_W2, rel_W3, pw_W3, maskp,
                                        maskf, na, w1T_rel, w2T_rel, w1T_pw, w2T_pw,
                                        w3T_rel, w3T_pw);
    mlp_kernel<<<2048, 256, 0, stream>>>(rel_feat, w1T_rel, w2T_rel, w3T_rel,
                                         rel_b1, rel_b2, rel_b3, S_rel);
    mlp_kernel<<<4, 256, 0, stream>>>(pw_feat, w1T_pw, w2T_pw, w3T_pw,
                                      pw_b1, pw_b2, pw_b3, S_pw);
    reduce_kernel<<<1024, 256, 0, stream>>>(S_rel, S_pw, rel_basis, pw_basis,
                                            maskf, na, out);
}